// Round 12
// baseline (22.367 us; speedup 1.0000x reference)
//
#include <hip/hip_runtime.h>

#define BATCH   65536
#define NREL    100
#define NBB     64            // bucketize blocks; each owns 1024 batch elements
#define NBX     8             // compute blocks per relation; each does 2x64 rows

typedef __attribute__((ext_vector_type(8))) short bf16x8;
typedef __attribute__((ext_vector_type(4))) float f32x4;

__device__ __forceinline__ unsigned short f2bf(float x) {   // RNE f32->bf16
    unsigned u = __float_as_uint(x);
    u += 0x7fffu + ((u >> 16) & 1u);
    return (unsigned short)(u >> 16);
}

// ---- Kernel A: prep = [blocks 0..63: counting sort] + [64..163: P->bf16] --
// Bucket entries packed as uint64 {b:16 | h<<16 (17b) | t<<33 (17b)} — read
// coalesced here so kernel B skips the random head/tail level (round-10 win)
// at half the bucket bytes. All ws cells rewritten every call -> no zeroing.
__launch_bounds__(256)
__global__ void transr_prep(const int* __restrict__ relation,
                            const int* __restrict__ head,
                            const int* __restrict__ tail,
                            const float* __restrict__ proj,
                            int* __restrict__ ws_hist,
                            int* __restrict__ ws_lpfx,
                            unsigned long long* __restrict__ ws_bucket,
                            unsigned short* __restrict__ ws_pbf) {
    const int tid = threadIdx.x, bid = blockIdx.x;

    if (bid < NBB) {
        __shared__ int hist[NREL];
        __shared__ int scan[128];

        for (int r = tid; r < NREL; r += 256) hist[r] = 0;
        __syncthreads();

        const int4 v  = ((const int4*)relation)[bid * 256 + tid];
        const int4 hv = ((const int4*)head)[bid * 256 + tid];
        const int4 tv = ((const int4*)tail)[bid * 256 + tid];
        const int vals[4] = {v.x, v.y, v.z, v.w};
        const int hs[4]   = {hv.x, hv.y, hv.z, hv.w};
        const int ts[4]   = {tv.x, tv.y, tv.z, tv.w};
        int lr[4];
        #pragma unroll
        for (int k = 0; k < 4; ++k) lr[k] = atomicAdd(&hist[vals[k]], 1);
        __syncthreads();

        if (tid < 128) scan[tid] = (tid < NREL) ? hist[tid] : 0;
        __syncthreads();
        #pragma unroll
        for (int off = 1; off < 128; off <<= 1) {      // Hillis-Steele inclusive
            int t = 0;
            if (tid < 128 && tid >= off) t = scan[tid - off];
            __syncthreads();
            if (tid < 128) scan[tid] += t;
            __syncthreads();
        }

        const int i0 = (bid * 256 + tid) * 4;
        #pragma unroll
        for (int k = 0; k < 4; ++k) {
            const int rel = vals[k];
            const unsigned long long e =
                (unsigned long long)(unsigned)(i0 + k)
                | ((unsigned long long)(unsigned)hs[k] << 16)
                | ((unsigned long long)(unsigned)ts[k] << 33);
            ws_bucket[bid * 1024 + (scan[rel] - hist[rel]) + lr[k]] = e;
        }
        for (int r = tid; r < NREL; r += 256) {
            ws_hist[r * NBB + bid] = hist[r];
            ws_lpfx[r * NBB + bid] = scan[r] - hist[r];
        }
    } else {
        const int rel = bid - NBB;
        const int n = tid >> 2, q = tid & 3;
        const float* Pr = proj + (size_t)rel * 4096;
        unsigned short* dst = ws_pbf + (size_t)rel * 4096;
        #pragma unroll
        for (int kh = 0; kh < 2; ++kh) {
            const int khi = q * 2 + kh;
            unsigned short u[8];
            #pragma unroll
            for (int klo = 0; klo < 8; ++klo)
                u[klo] = f2bf(Pr[(khi * 8 + klo) * 64 + n]);
            *(bf16x8*)&dst[n * 64 + ((khi ^ (n & 7)) << 3)] = *(bf16x8*)u;
        }
    }
}

// ---- Kernel B: 2 tiles (128 rows) per 256-thread block --------------------
// One scan, one 8 KB B-image load, ONE barrier serve both tiles. Each thread
// runs two independent gather chains (2x MLP vs round 11). 4 waves as in the
// validated structure (round 9's 512-thread variant is NOT reproduced).
// Value-bearing math identical to rounds 5-11 -> absmax stays exactly 128.
__launch_bounds__(256, 4)
__global__ void transr_compute(const float* __restrict__ ent,
                               const float* __restrict__ remb,
                               const int* __restrict__ ws_hist,
                               const int* __restrict__ ws_lpfx,
                               const unsigned long long* __restrict__ ws_bucket,
                               const unsigned short* __restrict__ ws_pbf,
                               float* __restrict__ out) {
    __shared__ unsigned short Abuf[2][64 * 64];  // D rows (bf16), XOR-swizzled
    __shared__ unsigned short Bbuf[64 * 64];     // P^T  (bf16), pre-swizzled image
    __shared__ int bidx_s[128];

    const int tid    = threadIdx.x;
    const int wid    = tid >> 6;
    const int lane   = tid & 63;
    const int rel    = blockIdx.y;
    const int start0 = blockIdx.x << 7;          // 128 rows per block

    // per-wave register scan of this relation's 64 per-srcblock counts
    const int hown = ws_hist[rel * NBB + lane];
    const int lpfx = ws_lpfx[rel * NBB + lane];
    int hinc = hown;
    #pragma unroll
    for (int m = 1; m < 64; m <<= 1) {
        int t = __shfl_up(hinc, m);
        if (lane >= m) hinc += t;
    }
    const int hexc = hinc - hown;                // exclusive prefix, lane-indexed
    const int cnt  = __shfl(hinc, 63);
    if (start0 >= cnt) return;                   // both tiles empty: uniform exit
    const bool has1 = (start0 + 64) < cnt;

    // independent B-image load issues early (latency hides under gather chains)
    const uint4* bsrc = (const uint4*)(ws_pbf + (size_t)rel * 4096) + tid * 2;
    const uint4 bimg0 = bsrc[0];
    const uint4 bimg1 = bsrc[1];

    // remb values for acc init (L1-broadcast), shared by both tiles
    const float* Rr = remb + rel * 64;
    float rv[4];
    #pragma unroll
    for (int f = 0; f < 4; ++f) rv[f] = Rr[f * 16 + (lane & 15)];

    // stage both tiles: thread = (row = tid>>2, quarter q = tid&3), 2 chains
    #pragma unroll
    for (int tt = 0; tt < 2; ++tt) {
        if (tt == 1 && !has1) break;
        const int row = tid >> 2, q = tid & 3;
        const int j  = start0 + tt * 64 + row;
        const int jj = (j < cnt) ? j : (cnt - 1);
        int lo = 0;                              // last c with hexc[c] <= jj
        #pragma unroll
        for (int s = 32; s; s >>= 1) {
            const int c = lo + s;
            const int v = __shfl(hexc, c & 63);
            if (c < 64 && v <= jj) lo = c;
        }
        const unsigned long long e =
            ws_bucket[lo * 1024 + __shfl(lpfx, lo) + (jj - __shfl(hexc, lo))];
        const int bx = (int)(e & 0xFFFFull);
        const int hh = (int)((e >> 16) & 0x1FFFFull);
        const int th = (int)((e >> 33) & 0x1FFFFull);
        if (q == 0) bidx_s[tt * 64 + row] = bx;
        const float4* h4 = (const float4*)(ent + (size_t)hh * 64) + q * 4;
        const float4* t4 = (const float4*)(ent + (size_t)th * 64) + q * 4;
        #pragma unroll
        for (int i = 0; i < 2; ++i) {
            unsigned short u[8];
            #pragma unroll
            for (int m = 0; m < 2; ++m) {
                float4 a = h4[i * 2 + m], c = t4[i * 2 + m];
                u[m * 4 + 0] = f2bf(a.x - c.x);
                u[m * 4 + 1] = f2bf(a.y - c.y);
                u[m * 4 + 2] = f2bf(a.z - c.z);
                u[m * 4 + 3] = f2bf(a.w - c.w);
            }
            const int slice = (q * 2 + i) ^ (row & 7);   // XOR swizzle
            *(bf16x8*)&Abuf[tt][row * 64 + slice * 8] = *(bf16x8*)u;
        }
    }
    {
        uint4* dst = (uint4*)Bbuf + tid * 2;
        dst[0] = bimg0;
        dst[1] = bimg1;
    }
    __syncthreads();                             // the only barrier

    // MFMA + epilogue per tile; wave strip = rows wid*16..+15 of the tile
    const int arow = wid * 16 + (lane & 15);
    const int g    = lane >> 4;
    #pragma unroll
    for (int tt = 0; tt < 2; ++tt) {
        if (tt == 1 && !has1) break;
        f32x4 acc[4];
        #pragma unroll
        for (int f = 0; f < 4; ++f) acc[f] = (f32x4){rv[f], rv[f], rv[f], rv[f]};

        #pragma unroll
        for (int s = 0; s < 2; ++s) {
            const int ks = g + s * 4;
            bf16x8 av = *(const bf16x8*)&Abuf[tt][arow * 64 + ((ks ^ (arow & 7)) * 8)];
            #pragma unroll
            for (int f = 0; f < 4; ++f) {
                const int col = f * 16 + (lane & 15);
                bf16x8 bv = *(const bf16x8*)&Bbuf[col * 64 + ((ks ^ (col & 7)) * 8)];
                acc[f] = __builtin_amdgcn_mfma_f32_16x16x32_bf16(av, bv, acc[f], 0, 0, 0);
            }
        }

        float ps[4];
        #pragma unroll
        for (int r = 0; r < 4; ++r)
            ps[r] = acc[0][r] * acc[0][r] + acc[1][r] * acc[1][r] +
                    acc[2][r] * acc[2][r] + acc[3][r] * acc[3][r];
        #pragma unroll
        for (int m = 1; m < 16; m <<= 1) {
            #pragma unroll
            for (int r = 0; r < 4; ++r) ps[r] += __shfl_xor(ps[r], m, 64);
        }
        if ((lane & 15) == 0) {
            const int rowb = wid * 16 + g * 4;
            #pragma unroll
            for (int r = 0; r < 4; ++r) {
                const int j = start0 + tt * 64 + rowb + r;
                if (j < cnt) out[bidx_s[tt * 64 + rowb + r]] = ps[r];
            }
        }
    }
}

extern "C" void kernel_launch(void* const* d_in, const int* in_sizes, int n_in,
                              void* d_out, int out_size, void* d_ws, size_t ws_size,
                              hipStream_t stream) {
    const int*   head     = (const int*)d_in[0];
    const int*   relation = (const int*)d_in[1];
    const int*   tail     = (const int*)d_in[2];
    const float* ent      = (const float*)d_in[3];
    const float* remb     = (const float*)d_in[4];
    const float* proj     = (const float*)d_in[5];
    float*       out      = (float*)d_out;

    // ws layout (every read cell rewritten each call -> no zeroing needed):
    int* ws_hist = (int*)d_ws;                              // [100*64] @ 0
    int* ws_lpfx = (int*)d_ws + 8192;                       // [100*64] @ 32 KB
    unsigned long long* ws_bucket =
        (unsigned long long*)((char*)d_ws + 65536);         // [64*1024] u64 @ 64 KB (512 KB)
    unsigned short* ws_pbf =
        (unsigned short*)((char*)d_ws + 1024 * 1024);       // [100*4096] @ 1 MB (800 KB)

    transr_prep<<<NBB + NREL, 256, 0, stream>>>(relation, head, tail, proj,
                                                ws_hist, ws_lpfx, ws_bucket, ws_pbf);
    transr_compute<<<dim3(NBX, NREL), 256, 0, stream>>>(
        ent, remb, ws_hist, ws_lpfx, ws_bucket, ws_pbf, out);
}

// Round 13
// 19.715 us; speedup vs baseline: 1.1345x; 1.1345x over previous
//
#include <hip/hip_runtime.h>

#define BATCH   65536
#define NREL    100
#define NBB     64            // counting-sort blocks; each owns 1024 batch elements
#define NGB     1024          // d-gather blocks; each owns 256 row-quarters
#define NTILE   16            // 16 x 64-row tiles per relation

typedef __attribute__((ext_vector_type(8))) short bf16x8;
typedef __attribute__((ext_vector_type(4))) float f32x4;

__device__ __forceinline__ unsigned short f2bf(float x) {   // RNE f32->bf16
    unsigned u = __float_as_uint(x);
    u += 0x7fffu + ((u >> 16) & 1u);
    return (unsigned short)(u >> 16);
}

// ---- Kernel A: prep = [0..63: counting sort] + [64..163: P->bf16 image]
//                     + [164..1187: d-gather] ------------------------------
// d-gather: dbuf[i] = bf16(ent[head[i]] - ent[tail[i]]), natural order, no
// dependent chain (the random ent reads happen HERE with max parallelism);
// compute then reads 128B bf16 rows that are L3-resident (just written).
// All ws cells rewritten every call -> no zeroing, no memset node.
__launch_bounds__(256)
__global__ void transr_prep(const int* __restrict__ relation,
                            const int* __restrict__ head,
                            const int* __restrict__ tail,
                            const float* __restrict__ proj,
                            const float* __restrict__ ent,
                            int* __restrict__ ws_hist,
                            int* __restrict__ ws_lpfx,
                            int* __restrict__ ws_bucket,
                            unsigned short* __restrict__ ws_pbf,
                            unsigned short* __restrict__ ws_dbuf) {
    const int tid = threadIdx.x, bid = blockIdx.x;

    if (bid < NBB) {
        // ---- counting sort (validated r7-r12); bucket stores b only (int)
        __shared__ int hist[NREL];
        __shared__ int scan[128];

        for (int r = tid; r < NREL; r += 256) hist[r] = 0;
        __syncthreads();

        const int4 v = ((const int4*)relation)[bid * 256 + tid];
        const int vals[4] = {v.x, v.y, v.z, v.w};
        int lr[4];
        #pragma unroll
        for (int k = 0; k < 4; ++k) lr[k] = atomicAdd(&hist[vals[k]], 1);
        __syncthreads();

        if (tid < 128) scan[tid] = (tid < NREL) ? hist[tid] : 0;
        __syncthreads();
        #pragma unroll
        for (int off = 1; off < 128; off <<= 1) {      // Hillis-Steele inclusive
            int t = 0;
            if (tid < 128 && tid >= off) t = scan[tid - off];
            __syncthreads();
            if (tid < 128) scan[tid] += t;
            __syncthreads();
        }

        const int i0 = (bid * 256 + tid) * 4;
        #pragma unroll
        for (int k = 0; k < 4; ++k) {
            const int rel = vals[k];
            ws_bucket[bid * 1024 + (scan[rel] - hist[rel]) + lr[k]] = i0 + k;
        }
        for (int r = tid; r < NREL; r += 256) {
            ws_hist[r * NBB + bid] = hist[r];
            ws_lpfx[r * NBB + bid] = scan[r] - hist[r];
        }
    } else if (bid < NBB + NREL) {
        // ---- P -> swizzled bf16 image (validated r8-r12)
        const int rel = bid - NBB;
        const int n = tid >> 2, q = tid & 3;
        const float* Pr = proj + (size_t)rel * 4096;
        unsigned short* dst = ws_pbf + (size_t)rel * 4096;
        #pragma unroll
        for (int kh = 0; kh < 2; ++kh) {
            const int khi = q * 2 + kh;
            unsigned short u[8];
            #pragma unroll
            for (int klo = 0; klo < 8; ++klo)
                u[klo] = f2bf(Pr[(khi * 8 + klo) * 64 + n]);
            *(bf16x8*)&dst[n * 64 + ((khi ^ (n & 7)) << 3)] = *(bf16x8*)u;
        }
    } else {
        // ---- d-gather: thread = (row = idx>>2, quarter q = idx&3)
        const int idx = (bid - NBB - NREL) * 256 + tid;
        const int row = idx >> 2, q = idx & 3;
        const int h = head[row], t = tail[row];
        const float4* h4 = (const float4*)(ent + (size_t)h * 64) + q * 4;
        const float4* t4 = (const float4*)(ent + (size_t)t * 64) + q * 4;
        unsigned short u[16];
        #pragma unroll
        for (int m = 0; m < 4; ++m) {
            float4 a = h4[m], c = t4[m];
            u[m * 4 + 0] = f2bf(a.x - c.x);
            u[m * 4 + 1] = f2bf(a.y - c.y);
            u[m * 4 + 2] = f2bf(a.z - c.z);
            u[m * 4 + 3] = f2bf(a.w - c.w);
        }
        bf16x8* dst = (bf16x8*)&ws_dbuf[(size_t)row * 64 + q * 16];
        dst[0] = *(bf16x8*)&u[0];
        dst[1] = *(bf16x8*)&u[8];
    }
}

// ---- Kernel B: MFMA per-(relation, 64-row tile) ---------------------------
// A-stage is now: search -> 4B bucket -> 32B bf16 copy from L3-resident dbuf.
// No f2bf, no f32 gather in this kernel. Value-bearing math identical to
// rounds 5-12 -> absmax stays exactly 128.
__launch_bounds__(256, 4)
__global__ void transr_compute(const float* __restrict__ remb,
                               const int* __restrict__ ws_hist,
                               const int* __restrict__ ws_lpfx,
                               const int* __restrict__ ws_bucket,
                               const unsigned short* __restrict__ ws_pbf,
                               const unsigned short* __restrict__ ws_dbuf,
                               float* __restrict__ out) {
    __shared__ unsigned short Abuf[64 * 64];   // D rows (bf16), XOR-swizzled slices
    __shared__ unsigned short Bbuf[64 * 64];   // P^T  (bf16), pre-swizzled image
    __shared__ int bidx_s[64];

    const int tid   = threadIdx.x;
    const int wid   = tid >> 6;
    const int lane  = tid & 63;
    const int rel   = blockIdx.y;
    const int start = blockIdx.x << 6;

    // per-wave register scan of this relation's 64 per-srcblock counts
    const int hown = ws_hist[rel * NBB + lane];
    const int lpfx = ws_lpfx[rel * NBB + lane];
    int hinc = hown;
    #pragma unroll
    for (int m = 1; m < 64; m <<= 1) {
        int t = __shfl_up(hinc, m);
        if (lane >= m) hinc += t;
    }
    const int hexc = hinc - hown;              // exclusive prefix, lane-indexed
    const int cnt  = __shfl(hinc, 63);
    if (start >= cnt) return;                  // empty tail tile: uniform exit

    // independent B-image load issues early
    const uint4* bsrc = (const uint4*)(ws_pbf + (size_t)rel * 4096) + tid * 2;
    const uint4 bimg0 = bsrc[0];
    const uint4 bimg1 = bsrc[1];

    // remb folded into acc init via direct L1-broadcast loads
    const float* Rr = remb + rel * 64;
    f32x4 acc[4];
    #pragma unroll
    for (int f = 0; f < 4; ++f) {
        const float rv = Rr[f * 16 + (lane & 15)];
        acc[f] = (f32x4){rv, rv, rv, rv};
    }

    // stage A: thread = (row = tid>>2, quarter q = tid&3); 32B bf16 copy
    {
        const int row = tid >> 2, q = tid & 3;
        const int j  = start + row;
        const int jj = (j < cnt) ? j : (cnt - 1);
        int lo = 0;                            // last c with hexc[c] <= jj
        #pragma unroll
        for (int s = 32; s; s >>= 1) {
            const int c = lo + s;
            const int v = __shfl(hexc, c & 63);
            if (c < 64 && v <= jj) lo = c;
        }
        const int b = ws_bucket[lo * 1024 + __shfl(lpfx, lo) + (jj - __shfl(hexc, lo))];
        if (q == 0) bidx_s[row] = b;
        const bf16x8* src = (const bf16x8*)&ws_dbuf[(size_t)b * 64 + q * 16];
        const bf16x8 u0 = src[0];
        const bf16x8 u1 = src[1];
        *(bf16x8*)&Abuf[row * 64 + (((q * 2)     ^ (row & 7)) * 8)] = u0;
        *(bf16x8*)&Abuf[row * 64 + (((q * 2 + 1) ^ (row & 7)) * 8)] = u1;
    }
    {
        uint4* dst = (uint4*)Bbuf + tid * 2;
        dst[0] = bimg0;
        dst[1] = bimg1;
    }
    __syncthreads();                           // the only barrier

    // MFMA: wave strip = rows wid*16..+15; 2 k-steps x 4 n-tiles
    const int arow = wid * 16 + (lane & 15);
    const int g    = lane >> 4;
    #pragma unroll
    for (int s = 0; s < 2; ++s) {
        const int ks = g + s * 4;
        bf16x8 av = *(const bf16x8*)&Abuf[arow * 64 + ((ks ^ (arow & 7)) * 8)];
        #pragma unroll
        for (int f = 0; f < 4; ++f) {
            const int col = f * 16 + (lane & 15);
            bf16x8 bv = *(const bf16x8*)&Bbuf[col * 64 + ((ks ^ (col & 7)) * 8)];
            acc[f] = __builtin_amdgcn_mfma_f32_16x16x32_bf16(av, bv, acc[f], 0, 0, 0);
        }
    }

    // epilogue: score = sum of squares; reduce across 16 col-lanes
    float ps[4];
    #pragma unroll
    for (int r = 0; r < 4; ++r)
        ps[r] = acc[0][r] * acc[0][r] + acc[1][r] * acc[1][r] +
                acc[2][r] * acc[2][r] + acc[3][r] * acc[3][r];
    #pragma unroll
    for (int m = 1; m < 16; m <<= 1) {
        #pragma unroll
        for (int r = 0; r < 4; ++r) ps[r] += __shfl_xor(ps[r], m, 64);
    }
    if ((lane & 15) == 0) {
        const int rowb = wid * 16 + g * 4;
        #pragma unroll
        for (int r = 0; r < 4; ++r) {
            const int j = start + rowb + r;
            if (j < cnt) out[bidx_s[rowb + r]] = ps[r];
        }
    }
}

extern "C" void kernel_launch(void* const* d_in, const int* in_sizes, int n_in,
                              void* d_out, int out_size, void* d_ws, size_t ws_size,
                              hipStream_t stream) {
    const int*   head     = (const int*)d_in[0];
    const int*   relation = (const int*)d_in[1];
    const int*   tail     = (const int*)d_in[2];
    const float* ent      = (const float*)d_in[3];
    const float* remb     = (const float*)d_in[4];
    const float* proj     = (const float*)d_in[5];
    float*       out      = (float*)d_out;

    // ws layout (every read cell rewritten each call -> no zeroing needed):
    int* ws_hist = (int*)d_ws;                              // [100*64] @ 0
    int* ws_lpfx = (int*)d_ws + 8192;                       // [100*64] @ 32 KB
    int* ws_bucket = (int*)((char*)d_ws + 65536);           // [64*1024] @ 64 KB (256 KB)
    unsigned short* ws_pbf =
        (unsigned short*)((char*)d_ws + 512 * 1024);        // [100*4096] @ 512 KB (800 KB)
    unsigned short* ws_dbuf =
        (unsigned short*)((char*)d_ws + 2 * 1024 * 1024);   // [65536*64] @ 2 MB (8.4 MB)

    transr_prep<<<NBB + NREL + NGB, 256, 0, stream>>>(
        relation, head, tail, proj, ent,
        ws_hist, ws_lpfx, ws_bucket, ws_pbf, ws_dbuf);
    transr_compute<<<dim3(NTILE, NREL), 256, 0, stream>>>(
        remb, ws_hist, ws_lpfx, ws_bucket, ws_pbf, ws_dbuf, out);
}